// Round 7
// baseline (308.483 us; speedup 1.0000x reference)
//
#include <hip/hip_runtime.h>
#include <hip/hip_bf16.h>
#include <math.h>

// audio (16,5,256) -> 4 branches x 3 mamba layers -> gates scale x1..x4.
// 64 (branch,batch) groups x 4 member-blocks = 256 blocks x 512 threads.
// Member q owns d_inner slice [128q,128q+128) for in_proj/conv; ONE exchange
// per layer (xc,z slices, 20KB/group) via agent-scope barrier; x_proj/dt/scan/
// out_proj are then computed redundantly per member so `a` stays block-local.
// This minimizes agent-scope acquire rounds (each one invalidates L2 on CDNA4).

#define NTOK 80
#define DM   256
#define DI   512

typedef float f32x4 __attribute__((ext_vector_type(4)));

__device__ __forceinline__ float silu_f(float v) {
    return v / (1.f + expf(-v));
}
__device__ __forceinline__ float dot4(float4 a, float4 b) {
    return a.x*b.x + a.y*b.y + a.z*b.z + a.w*b.w;
}

// ---- workspace layout (float indices) ----
#define OFF_SG    0          // 81920
#define OFF_WINT  81920      // 12 * 262144   [64 k4][1024 c] f4
#define OFF_WOUTT 3227648    // 12 * 131072   [128 k4][256 c] f4
#define OFF_WXT   4800512    // 12 * 24576    [128 k4][48 c]  f4
#define OFF_GWT   5095424    // 4  * 65536    [64 k4][256 c]  f4
#define OFF_XCZP  5357568    // 64 groups * 4 q * 1280 (xc|z slices)
#define OFF_BAR   5685248    // 1024 uints (64 groups * 16, 64B apart)

// ---------------- weight repack: float4-element transpose [R][C4] -> [C4][R] ---
__global__ __launch_bounds__(256) void k_tr(const float* __restrict__ Win,
                                            const float* __restrict__ Wout,
                                            const float* __restrict__ Wx,
                                            const float* __restrict__ gw,
                                            float* __restrict__ ws) {
    if (blockIdx.x == 0) {   // zero group-barrier counters (deterministic per call)
        unsigned* barp = (unsigned*)(ws + OFF_BAR);
        #pragma unroll
        for (int j = 0; j < 4; ++j) barp[j * 256 + threadIdx.x] = 0u;
    }
    int b = blockIdx.x;
    const float4* src; float4* dst; int R, C4, tile;
    if (b < 768) {                        // Win: 12 x [1024][64]f4
        int mat = b >> 6; tile = b & 63; R = 1024; C4 = 64;
        src = (const float4*)Win + (size_t)mat * 65536;
        dst = (float4*)(ws + OFF_WINT) + (size_t)mat * 65536;
    } else if (b < 1152) {                // Wout: 12 x [256][128]f4
        int bb = b - 768; int mat = bb >> 5; tile = bb & 31; R = 256; C4 = 128;
        src = (const float4*)Wout + (size_t)mat * 32768;
        dst = (float4*)(ws + OFF_WOUTT) + (size_t)mat * 32768;
    } else if (b < 1248) {                // Wx: 12 x [48][128]f4
        int bb = b - 1152; int mat = bb >> 3; tile = bb & 7; R = 48; C4 = 128;
        src = (const float4*)Wx + (size_t)mat * 6144;
        dst = (float4*)(ws + OFF_WXT) + (size_t)mat * 6144;
    } else {                              // gw: 4 x [256][64]f4
        int bb = b - 1248; int mat = bb >> 4; tile = bb & 15; R = 256; C4 = 64;
        src = (const float4*)gw + (size_t)mat * 16384;
        dst = (float4*)(ws + OFF_GWT) + (size_t)mat * 16384;
    }
    int tilesC = C4 >> 5;
    int r0 = (tile / tilesC) << 5, c0 = (tile % tilesC) << 5;
    __shared__ float4 t[32][33];
    int tx = threadIdx.x & 31, ty = threadIdx.x >> 5;
#pragma unroll
    for (int j = 0; j < 4; ++j) {
        int r = ty + j * 8;
        if (r0 + r < R) t[r][tx] = src[(size_t)(r0 + r) * C4 + c0 + tx];
    }
    __syncthreads();
#pragma unroll
    for (int j = 0; j < 4; ++j) {
        int cc = ty + j * 8;
        if (r0 + tx < R) dst[(size_t)(c0 + cc) * R + r0 + tx] = t[tx][cc];
    }
}

// 4-member group barrier; agent scope so correctness is XCD-placement-free.
__device__ __forceinline__ void gbar(unsigned* slot) {
    __syncthreads();   // all threads' global stores drained (write-through to L2)
    if (threadIdx.x == 0) {
        __hip_atomic_fetch_add(slot, 1u, __ATOMIC_RELEASE, __HIP_MEMORY_SCOPE_AGENT);
        while (__hip_atomic_load(slot, __ATOMIC_RELAXED, __HIP_MEMORY_SCOPE_AGENT) < 4u)
            __builtin_amdgcn_s_sleep(1);
        (void)__hip_atomic_load(slot, __ATOMIC_ACQUIRE, __HIP_MEMORY_SCOPE_AGENT);
    }
    __syncthreads();
}

// ---------------- split mamba chain + gates: 256 blocks x 512 threads ----------
__global__ __launch_bounds__(512) void k_chain4(
    const float* __restrict__ audio,
    const float* __restrict__ ln_g, const float* __restrict__ ln_b,
    const float* __restrict__ Wc,   const float* __restrict__ bc,
    const float* __restrict__ Wdt,  const float* __restrict__ bdt,
    const float* __restrict__ Alog, const float* __restrict__ Dp,
    const float* __restrict__ gb,   float* __restrict__ ws)
{
    int gid = blockIdx.x & 63;    // group = (branch,batch)
    int q   = blockIdx.x >> 6;    // member 0..3 (blockIdx = gid + 64q: same XCD)
    int i = gid & 3, b = gid >> 2;
    int tid = threadIdx.x, lane = tid & 63, wave = tid >> 6;
    int dq = q * 128;             // own d_inner slice start

    float* s_g  = ws + OFF_SG;
    float* xczp = ws + OFF_XCZP + (size_t)gid * 5120;
    unsigned* bar = (unsigned*)(ws + OFF_BAR) + gid * 16;

    __shared__ __align__(16) float a_l   [1280];  // activations (5x256), full
    __shared__ __align__(16) float aln_l [1280];  // LN out, full
    __shared__ __align__(16) float xz_l  [1280];  // own: [r][0..127]=xc-pre, [128..255]=z
    __shared__ __align__(16) float xc_f  [2560];  // full conv+silu out (5x512)
    __shared__ __align__(16) float z_f   [2560];  // full z (5x512)
    __shared__ __align__(16) float y_f   [2560];  // full scan out (5x512)
    __shared__ __align__(16) float dbl_l [240];
    __shared__ __align__(16) float part_l[2560];  // K-split scratch

    for (int v = tid; v < 320; v += 512)
        ((float4*)a_l)[v] = ((const float4*)(audio + (size_t)b * 1280))[v];
    __syncthreads();

    for (int l = 0; l < 3; ++l) {
        int il = i * 3 + l;

        // ---- LayerNorm (redundant): wave w<5 handles row w ----
        if (wave < 5) {
            float4 x = ((float4*)a_l)[wave*64 + lane];
            float s = x.x + x.y + x.z + x.w;
            #pragma unroll
            for (int o = 32; o > 0; o >>= 1) s += __shfl_down(s, o, 64);
            float mu = __shfl(s, 0, 64) * (1.f/256.f);
            float4 d = make_float4(x.x-mu, x.y-mu, x.z-mu, x.w-mu);
            float v2 = d.x*d.x + d.y*d.y + d.z*d.z + d.w*d.w;
            #pragma unroll
            for (int o = 32; o > 0; o >>= 1) v2 += __shfl_down(v2, o, 64);
            float rstd = rsqrtf(__shfl(v2, 0, 64) * (1.f/256.f) + 1e-5f);
            float4 g4 = ((const float4*)(ln_g + (size_t)il*DM))[lane];
            float4 b4 = ((const float4*)(ln_b + (size_t)il*DM))[lane];
            ((float4*)aln_l)[wave*64 + lane] =
                make_float4(d.x*rstd*g4.x + b4.x, d.y*rstd*g4.y + b4.y,
                            d.z*rstd*g4.z + b4.z, d.w*rstd*g4.w + b4.w);
        }
        __syncthreads();

        // ---- in_proj: own 256 cols (128 xc + 128 z), K=256 split 2 (kh) ----
        {
            int cl = tid & 255, kh = tid >> 8;
            int gcol = (cl < 128) ? (dq + cl) : (384 + dq + cl);
            const float4* wp = (const float4*)(ws + OFF_WINT) + (size_t)il*65536 + gcol;
            const float4* a4 = (const float4*)aln_l;
            float ac0=0.f, ac1=0.f, ac2=0.f, ac3=0.f, ac4=0.f;
            #pragma unroll 8
            for (int kk = 0; kk < 32; ++kk) {
                int k4 = kh*32 + kk;
                float4 w = wp[(size_t)k4*1024];
                ac0 += dot4(w, a4[k4]);      ac1 += dot4(w, a4[64+k4]);
                ac2 += dot4(w, a4[128+k4]);  ac3 += dot4(w, a4[192+k4]);
                ac4 += dot4(w, a4[256+k4]);
            }
            part_l[kh*1280 +       cl] = ac0;  part_l[kh*1280 + 256 + cl] = ac1;
            part_l[kh*1280 + 512 + cl] = ac2;  part_l[kh*1280 + 768 + cl] = ac3;
            part_l[kh*1280 +1024 + cl] = ac4;
        }
        __syncthreads();
        for (int v = tid; v < 1280; v += 512) xz_l[v] = part_l[v] + part_l[1280 + v];
        __syncthreads();

        // ---- conv(k=4)+SiLU on own slice; publish (xc,z) slice to ws ----
        for (int v = tid; v < 1280; v += 512) {
            int r = v >> 8, c = v & 255;
            float val;
            if (c < 128) {
                int d = dq + c;
                float acc = bc[(size_t)il*DI + d];
                const float* wr = Wc + ((size_t)il*DI + d)*4;
                #pragma unroll
                for (int k = 0; k < 4; ++k) {
                    int ts = r + k - 3;
                    if (ts >= 0) acc += wr[k] * xz_l[ts*256 + c];
                }
                val = silu_f(acc);
            } else {
                val = xz_l[v];
            }
            xczp[q*1280 + v] = val;
        }
        gbar(bar + l);                        // ONE coherence round per layer

        // ---- assemble full xc, z from all 4 slices ----
        #pragma unroll
        for (int q2 = 0; q2 < 4; ++q2)
            for (int v = tid; v < 1280; v += 512) {
                int r = v >> 8, c = v & 255;
                float val = xczp[q2*1280 + v];
                if (c < 128) xc_f[r*512 + q2*128 + c] = val;
                else         z_f [r*512 + q2*128 + (c & 127)] = val;
            }
        __syncthreads();

        // ---- x_proj full (redundant): 48 cols x 5 rows, K=512 split 2 ----
        if (tid < 480) {
            int c = tid % 48, r = (tid / 48) % 5, kh = tid / 240;
            const float4* wp = (const float4*)(ws + OFF_WXT) + (size_t)il*6144 + c;
            const float4* x4 = (const float4*)xc_f + r*128 + kh*64;
            float acc = 0.f;
            #pragma unroll 8
            for (int kk = 0; kk < 64; ++kk)
                acc += dot4(wp[(size_t)(kh*64 + kk)*48], x4[kk]);
            part_l[tid] = acc;
        }
        __syncthreads();
        if (tid < 240) dbl_l[tid] = part_l[tid] + part_l[240 + tid];
        __syncthreads();

        // ---- dt-proj + scan + D skip + z gate, full 512 channels ----
        {
            int d = tid;
            float A[16], h[16];
            const float4* al4 = (const float4*)(Alog + ((size_t)il*DI + d)*16);
            float4 av0 = al4[0], av1 = al4[1], av2 = al4[2], av3 = al4[3];
            A[0]=-expf(av0.x); A[1]=-expf(av0.y); A[2]=-expf(av0.z); A[3]=-expf(av0.w);
            A[4]=-expf(av1.x); A[5]=-expf(av1.y); A[6]=-expf(av1.z); A[7]=-expf(av1.w);
            A[8]=-expf(av2.x); A[9]=-expf(av2.y); A[10]=-expf(av2.z); A[11]=-expf(av2.w);
            A[12]=-expf(av3.x); A[13]=-expf(av3.y); A[14]=-expf(av3.z); A[15]=-expf(av3.w);
            #pragma unroll
            for (int n = 0; n < 16; ++n) h[n] = 0.f;
            const float4* wd4 = (const float4*)(Wdt + ((size_t)il*DI + d)*16);
            float4 w0 = wd4[0], w1 = wd4[1], w2 = wd4[2], w3 = wd4[3];
            float bdtv = bdt[(size_t)il*DI + d];
            float dv   = Dp[(size_t)il*DI + d];
            #pragma unroll
            for (int t = 0; t < 5; ++t) {
                const float* db = dbl_l + t*48;
                float acc = bdtv;
                acc += db[0]*w0.x + db[1]*w0.y + db[2]*w0.z + db[3]*w0.w;
                acc += db[4]*w1.x + db[5]*w1.y + db[6]*w1.z + db[7]*w1.w;
                acc += db[8]*w2.x + db[9]*w2.y + db[10]*w2.z + db[11]*w2.w;
                acc += db[12]*w3.x + db[13]*w3.y + db[14]*w3.z + db[15]*w3.w;
                float dtv = fmaxf(acc, 0.f) + log1pf(expf(-fabsf(acc)));
                float xv  = xc_f[t*512 + d];
                float zv  = z_f [t*512 + d];
                float dx  = dtv * xv;
                float yacc = 0.f;
                #pragma unroll
                for (int n = 0; n < 16; ++n) {
                    h[n] = expf(dtv*A[n])*h[n] + dx*db[16 + n];
                    yacc += h[n]*db[32 + n];
                }
                y_f[t*512 + d] = (yacc + xv*dv) * silu_f(zv);
            }
        }
        __syncthreads();

        // ---- out_proj FULL (redundant): 256 cols, K=512 split 2 (kh) ----
        {
            int c = tid & 255, kh = tid >> 8;
            const float4* wp = (const float4*)(ws + OFF_WOUTT) + (size_t)il*32768 + c;
            const float4* yy = (const float4*)y_f;   // [5][128]
            float ac0=0.f, ac1=0.f, ac2=0.f, ac3=0.f, ac4=0.f;
            #pragma unroll 8
            for (int kk = 0; kk < 64; ++kk) {
                int k4 = kh*64 + kk;
                float4 w = wp[(size_t)k4*256];
                ac0 += dot4(w, yy[k4]);      ac1 += dot4(w, yy[128+k4]);
                ac2 += dot4(w, yy[256+k4]);  ac3 += dot4(w, yy[384+k4]);
                ac4 += dot4(w, yy[512+k4]);
            }
            part_l[kh*1280 +       c] = ac0;  part_l[kh*1280 + 256 + c] = ac1;
            part_l[kh*1280 + 512 + c] = ac2;  part_l[kh*1280 + 768 + c] = ac3;
            part_l[kh*1280 +1024 + c] = ac4;
        }
        __syncthreads();
        for (int v = tid; v < 1280; v += 512)
            a_l[v] = aln_l[v] + part_l[v] + part_l[1280 + v];
        __syncthreads();
    }

    // ---- gates: own 64 cols, K=256 split 8 (kq); write s_g permuted ----
    {
        int cl = tid & 63, kq = tid >> 6;
        int cg = q*64 + cl;
        const float4* wp = (const float4*)(ws + OFF_GWT) + (size_t)i*16384 + cg;
        const float4* a4 = (const float4*)a_l;   // [5][64] f4
        float ac0=0.f, ac1=0.f, ac2=0.f, ac3=0.f, ac4=0.f;
        #pragma unroll 8
        for (int kk = 0; kk < 8; ++kk) {
            int k4 = kq*8 + kk;
            float4 w = wp[(size_t)k4*256];
            ac0 += dot4(w, a4[k4]);      ac1 += dot4(w, a4[64+k4]);
            ac2 += dot4(w, a4[128+k4]);  ac3 += dot4(w, a4[192+k4]);
            ac4 += dot4(w, a4[256+k4]);
        }
        part_l[kq*320 +       cl] = ac0;  part_l[kq*320 +  64 + cl] = ac1;
        part_l[kq*320 + 128 + cl] = ac2;  part_l[kq*320 + 192 + cl] = ac3;
        part_l[kq*320 + 256 + cl] = ac4;
    }
    __syncthreads();
    for (int v = tid; v < 320; v += 512) {
        int r = v >> 6, cl = v & 63;
        int cg = q*64 + cl;
        float acc = gb[(size_t)i*DM + cg];
        #pragma unroll
        for (int kq = 0; kq < 8; ++kq) acc += part_l[kq*320 + v];
        int row = b*5 + r;
        int np  = (i == 0) ? row : (r*16 + b);
        s_g[((size_t)i*NTOK + np)*DM + cg] = 1.f + silu_f(acc);
    }
}

// ---------------- fused elementwise: o = x * s[plane], nontemporal streaming ---
__global__ __launch_bounds__(256) void k_elem(
    const float* __restrict__ x1, const float* __restrict__ x2,
    const float* __restrict__ x3, const float* __restrict__ x4,
    const float* __restrict__ audio, const float* __restrict__ s_g,
    float* __restrict__ out) {
    int b = blockIdx.x;
    int t = threadIdx.x;

    if (b < 512) {
        // o4: HW=49 (odd) -> per-component plane index
        const float* s = s_g + 3 * NTOK * DM;
        const f32x4* xv = (const f32x4*)x4;
        f32x4* ov = (f32x4*)out;
        const int total4 = 1003520 / 4;
        for (int v = b * 256 + t; v < total4; v += 512 * 256) {
            f32x4 x = __builtin_nontemporal_load(&xv[v]);
#pragma unroll
            for (int j = 0; j < 4; ++j) {
                int idx = v * 4 + j;
                x[j] *= s[idx / 49];
            }
            __builtin_nontemporal_store(x, &ov[v]);
        }
    } else if (b < 1024) {
        const float* s = s_g + 2 * NTOK * DM;
        const f32x4* xv = (const f32x4*)x3;
        f32x4* ov = (f32x4*)(out + 1003520);
        const int total4 = 4014080 / 4;
        for (int v = (b - 512) * 256 + t; v < total4; v += 512 * 256) {
            float f = s[v / 49];
            f32x4 x = __builtin_nontemporal_load(&xv[v]);
            x *= f;
            __builtin_nontemporal_store(x, &ov[v]);
        }
    } else if (b < 2048) {
        const float* s = s_g + 1 * NTOK * DM;
        const f32x4* xv = (const f32x4*)x2;
        f32x4* ov = (f32x4*)(out + 5017600);
        const int total4 = 16056320 / 4;
        for (int v = (b - 1024) * 256 + t; v < total4; v += 1024 * 256) {
            float f = s[v / 196];
            f32x4 x = __builtin_nontemporal_load(&xv[v]);
            x *= f;
            __builtin_nontemporal_store(x, &ov[v]);
        }
    } else if (b < 6144) {
        const float* s = s_g;
        const f32x4* xv = (const f32x4*)x1;
        f32x4* ov = (f32x4*)(out + 21073920);
        const int total4 = 64225280 / 4;
        for (int v = (b - 2048) * 256 + t; v < total4; v += 4096 * 256) {
            float f = s[v / 784];
            f32x4 x = __builtin_nontemporal_load(&xv[v]);
            x *= f;
            __builtin_nontemporal_store(x, &ov[v]);
        }
    } else {
        int idx = (b - 6144) * 256 + t;
        out[85299200 + idx] = audio[idx];
    }
}

extern "C" void kernel_launch(void* const* d_in, const int* in_sizes, int n_in,
                              void* d_out, int out_size, void* d_ws, size_t ws_size,
                              hipStream_t stream) {
    const float* x1        = (const float*)d_in[0];
    const float* x2        = (const float*)d_in[1];
    const float* x3        = (const float*)d_in[2];
    const float* x4        = (const float*)d_in[3];
    const float* audio     = (const float*)d_in[4];
    const float* ln_g      = (const float*)d_in[5];
    const float* ln_b      = (const float*)d_in[6];
    const float* in_proj_w = (const float*)d_in[7];
    const float* conv_w    = (const float*)d_in[8];
    const float* conv_b    = (const float*)d_in[9];
    const float* xproj_w   = (const float*)d_in[10];
    const float* dt_w      = (const float*)d_in[11];
    const float* dt_b      = (const float*)d_in[12];
    const float* A_log     = (const float*)d_in[13];
    const float* Dvec      = (const float*)d_in[14];
    const float* out_proj_w= (const float*)d_in[15];
    const float* gate_w    = (const float*)d_in[16];
    const float* gate_b    = (const float*)d_in[17];

    float* ws = (float*)d_ws;

    k_tr<<<1312, 256, 0, stream>>>(in_proj_w, out_proj_w, xproj_w, gate_w, ws);
    k_chain4<<<256, 512, 0, stream>>>(audio, ln_g, ln_b, conv_w, conv_b,
                                      dt_w, dt_b, A_log, Dvec, gate_b, ws);
    k_elem<<<6224, 256, 0, stream>>>(x1, x2, x3, x4, audio, ws + OFF_SG,
                                     (float*)d_out);
}

// Round 8
// 278.212 us; speedup vs baseline: 1.1088x; 1.1088x over previous
//
#include <hip/hip_runtime.h>
#include <hip/hip_bf16.h>
#include <math.h>

// audio (16,5,256) -> 4 branches x 3 mamba layers -> gates scale x1..x4.
// Stage-pipelined mini-GEMMs, no inter-block sync (kernel boundaries only).
// Key model (R5-R7 evidence): chain was weight-RE-STREAMING bound (~336MB of
// L2/L3 traffic re-reading 21MB of weights per batch-group). Now the token
// dimension lives INSIDE blocks: each weight byte read ~4-8x total, amortized
// over 80 tokens. Conv is register-local (thread owns one channel x 5 tokens).

#define NTOK 80
#define DM   256
#define DI   512

typedef float f32x4 __attribute__((ext_vector_type(4)));

__device__ __forceinline__ float silu_f(float v) {
    return v / (1.f + expf(-v));
}
__device__ __forceinline__ float dot4(float4 a, float4 b) {
    return a.x*b.x + a.y*b.y + a.z*b.z + a.w*b.w;
}

// ---- workspace layout (float indices) ----
#define OFF_SG    0          // 81920   gates
#define OFF_A     81920      // 81920   a (post-layer activations) [4][80][256]
#define OFF_ALN   163840     // 81920   LN output (residual base)  [4][80][256]
#define OFF_XC    245760     // 163840  conv+silu out [4][80][512]
#define OFF_Z     409600     // 163840  z [4][80][512]
#define OFF_Y     573440     // 163840  scan out [4][80][512]
#define OFF_WINR  737280     // 3145728 [12][16 s][64 k4][64 j] f4 (j: 32 xc|32 z)
#define OFF_WOUTR 3883008    // 1572864 [12][8 s][128 k4][32 j] f4
#define OFF_WXT   5455872    // 294912  [12][128 k4][48 c] f4
#define OFF_GWR   5750784    // 262144  [4][8 s][64 k4][32 j] f4

// ---------------- weight repack (344 blocks x 256) ----------------
__global__ __launch_bounds__(256) void k_tr(const float* __restrict__ Win,
                                            const float* __restrict__ Wout,
                                            const float* __restrict__ Wx,
                                            const float* __restrict__ gw,
                                            float* __restrict__ ws) {
    __shared__ float4 T[4160];   // 65 KB scratch
    int b = blockIdx.x, tid = threadIdx.x;

    if (b < 192) {               // WinR: per (il, s): 64 cols x 64 k4
        int il = b >> 4, s = b & 15;
        const float4* src = (const float4*)Win + (size_t)il * 65536;
        float4* dst = (float4*)(ws + OFF_WINR) + ((size_t)il * 16 + s) * 4096;
        for (int idx = tid; idx < 4096; idx += 256) {
            int jj = idx >> 6, k4 = idx & 63;
            int c = (jj < 32) ? (32 * s + jj) : (512 + 32 * s + jj - 32);
            T[jj * 65 + k4] = src[(size_t)c * 64 + k4];
        }
        __syncthreads();
        for (int idx = tid; idx < 4096; idx += 256) {
            int k4 = idx >> 6, jj = idx & 63;
            dst[idx] = T[jj * 65 + k4];
        }
    } else if (b < 288) {        // WoutR: per (il, s): 32 cols x 128 k4
        int bb = b - 192; int il = bb >> 3, s = bb & 7;
        const float4* src = (const float4*)Wout + (size_t)il * 32768;
        float4* dst = (float4*)(ws + OFF_WOUTR) + ((size_t)il * 8 + s) * 4096;
        for (int idx = tid; idx < 4096; idx += 256) {
            int jj = idx >> 7, k4 = idx & 127;
            T[jj * 129 + k4] = src[(size_t)(32 * s + jj) * 128 + k4];
        }
        __syncthreads();
        for (int idx = tid; idx < 4096; idx += 256) {
            int k4 = idx >> 5, jj = idx & 31;
            dst[idx] = T[jj * 129 + k4];
        }
    } else if (b < 312) {        // WxT: per (il, half): 48 cols x 64 k4
        int bb = b - 288; int il = bb >> 1, h = bb & 1;
        const float4* src = (const float4*)Wx + (size_t)il * 6144;
        float4* dst = (float4*)(ws + OFF_WXT) + (size_t)il * 6144;
        for (int idx = tid; idx < 3072; idx += 256) {
            int jj = idx >> 6, k4l = idx & 63;
            T[jj * 65 + k4l] = src[(size_t)jj * 128 + 64 * h + k4l];
        }
        __syncthreads();
        for (int idx = tid; idx < 3072; idx += 256) {
            int k4l = idx / 48, jj = idx % 48;
            dst[(size_t)(64 * h + k4l) * 48 + jj] = T[jj * 65 + k4l];
        }
    } else {                     // GwR: per (i, s): 32 cols x 64 k4
        int bb = b - 312; int i = bb >> 3, s = bb & 7;
        const float4* src = (const float4*)gw + (size_t)i * 16384;
        float4* dst = (float4*)(ws + OFF_GWR) + ((size_t)i * 8 + s) * 2048;
        for (int idx = tid; idx < 2048; idx += 256) {
            int jj = idx >> 6, k4 = idx & 63;
            T[jj * 65 + k4] = src[(size_t)(32 * s + jj) * 64 + k4];
        }
        __syncthreads();
        for (int idx = tid; idx < 2048; idx += 256) {
            int k4 = idx >> 5, jj = idx & 31;
            dst[idx] = T[jj * 65 + k4];
        }
    }
}

// ---------------- K_in: LN + in_proj + conv + SiLU ----------------
// grid 256: tg = blk>>6 (20-token group), i = (blk>>4)&3, s = blk&15 (32ch)
__global__ __launch_bounds__(256) void K_in(
    const float* __restrict__ src, int srcStride,   // audio (0) or a_ws (20480)
    const float* __restrict__ ln_g, const float* __restrict__ ln_b,
    const float* __restrict__ Wc,   const float* __restrict__ bc,
    int l, float* __restrict__ ws)
{
    int blk = blockIdx.x;
    int tg = blk >> 6, i = (blk >> 4) & 3, s = blk & 15;
    int il = i * 3 + l;
    int tid = threadIdx.x, lane = tid & 63, wave = tid >> 6;
    int t0 = tg * 20;

    __shared__ __align__(16) float aln_s[20 * DM];

    // LN for 20 tokens: wave w handles tokens 5w..5w+4
    const float4* s4 = (const float4*)(src + (size_t)i * srcStride);
    float4 g4 = ((const float4*)(ln_g + (size_t)il * DM))[lane];
    float4 b4 = ((const float4*)(ln_b + (size_t)il * DM))[lane];
    bool wr_aln = (s == 0);
    float4* aln_ws4 = (float4*)(ws + OFF_ALN + (size_t)i * NTOK * DM);
    for (int r = 0; r < 5; ++r) {
        int n = t0 + wave * 5 + r;
        float4 x = s4[(size_t)n * 64 + lane];
        float sm = x.x + x.y + x.z + x.w;
        #pragma unroll
        for (int o = 32; o > 0; o >>= 1) sm += __shfl_down(sm, o, 64);
        float mu = __shfl(sm, 0, 64) * (1.f / 256.f);
        float4 d = make_float4(x.x - mu, x.y - mu, x.z - mu, x.w - mu);
        float v2 = d.x*d.x + d.y*d.y + d.z*d.z + d.w*d.w;
        #pragma unroll
        for (int o = 32; o > 0; o >>= 1) v2 += __shfl_down(v2, o, 64);
        float rstd = rsqrtf(__shfl(v2, 0, 64) * (1.f / 256.f) + 1e-5f);
        float4 o4 = make_float4(d.x*rstd*g4.x + b4.x, d.y*rstd*g4.y + b4.y,
                                d.z*rstd*g4.z + b4.z, d.w*rstd*g4.w + b4.w);
        ((float4*)aln_s)[(wave * 5 + r) * 64 + lane] = o4;
        if (wr_aln) aln_ws4[(size_t)n * 64 + lane] = o4;
    }
    __syncthreads();

    // GEMV: thread = (col j in slice, batch tq); 5 tokens in registers
    int j = tid & 63, tq = tid >> 6;
    const float4* wp = (const float4*)(ws + OFF_WINR) + ((size_t)il * 16 + s) * 4096 + j;
    const float4* a4 = (const float4*)aln_s + tq * 5 * 64;
    float ac0 = 0.f, ac1 = 0.f, ac2 = 0.f, ac3 = 0.f, ac4 = 0.f;
    #pragma unroll 8
    for (int k4 = 0; k4 < 64; ++k4) {
        float4 w = wp[(size_t)k4 * 64];
        ac0 += dot4(w, a4[k4]);        ac1 += dot4(w, a4[64 + k4]);
        ac2 += dot4(w, a4[128 + k4]);  ac3 += dot4(w, a4[192 + k4]);
        ac4 += dot4(w, a4[256 + k4]);
    }
    int nb = t0 + tq * 5;             // first token of this thread's batch
    if (j < 32) {
        int ch = 32 * s + j;
        const float* wc = Wc + ((size_t)il * DI + ch) * 4;
        float w0 = wc[0], w1 = wc[1], w2 = wc[2], w3 = wc[3];
        float bb = bc[(size_t)il * DI + ch];
        float x0 = bb + w3*ac0;
        float x1 = bb + w2*ac0 + w3*ac1;
        float x2 = bb + w1*ac0 + w2*ac1 + w3*ac2;
        float x3 = bb + w0*ac0 + w1*ac1 + w2*ac2 + w3*ac3;
        float x4 = bb + w0*ac1 + w1*ac2 + w2*ac3 + w3*ac4;
        float* xc = ws + OFF_XC + ((size_t)i * NTOK + nb) * DI + ch;
        xc[0]      = silu_f(x0);  xc[DI]     = silu_f(x1);
        xc[2*DI]   = silu_f(x2);  xc[3*DI]   = silu_f(x3);
        xc[4*DI]   = silu_f(x4);
    } else {
        int ch = 32 * s + (j - 32);
        float* z = ws + OFF_Z + ((size_t)i * NTOK + nb) * DI + ch;
        z[0] = ac0;  z[DI] = ac1;  z[2*DI] = ac2;  z[3*DI] = ac3;  z[4*DI] = ac4;
    }
}

// ---------------- K_scan: x_proj + dt + scan + D + z-gate ----------------
// grid 64: i = blk&3, b = blk>>2; 512 threads
__global__ __launch_bounds__(512) void K_scan(
    const float* __restrict__ Wdt, const float* __restrict__ bdt,
    const float* __restrict__ Alog, const float* __restrict__ Dp,
    int l, float* __restrict__ ws)
{
    int blk = blockIdx.x;
    int i = blk & 3, b = blk >> 2;
    int il = i * 3 + l;
    int tid = threadIdx.x;

    __shared__ __align__(16) float xc_l[5 * DI];
    __shared__ __align__(16) float dbl_l[240];
    __shared__ __align__(16) float xp_l[480];

    const float* xc_ws = ws + OFF_XC + ((size_t)i * NTOK + b * 5) * DI;
    for (int v = tid; v < 640; v += 512)
        ((float4*)xc_l)[v] = ((const float4*)xc_ws)[v];
    __syncthreads();

    // x_proj: 48 cols x 5 rows, K=512 split 2
    if (tid < 480) {
        int c = tid % 48, r = (tid / 48) % 5, kh = tid / 240;
        const float4* wp = (const float4*)(ws + OFF_WXT) + (size_t)il * 6144 + c;
        const float4* x4 = (const float4*)xc_l + r * 128 + kh * 64;
        float acc = 0.f;
        #pragma unroll 8
        for (int kk = 0; kk < 64; ++kk)
            acc += dot4(wp[(size_t)(kh * 64 + kk) * 48], x4[kk]);
        xp_l[tid] = acc;
    }
    __syncthreads();
    if (tid < 240) dbl_l[tid] = xp_l[tid] + xp_l[240 + tid];
    __syncthreads();

    // dt-proj + scan + D + z-gate: thread = channel
    {
        int d = tid;
        float A[16], h[16];
        const float4* al4 = (const float4*)(Alog + ((size_t)il * DI + d) * 16);
        float4 av0 = al4[0], av1 = al4[1], av2 = al4[2], av3 = al4[3];
        A[0]=-expf(av0.x); A[1]=-expf(av0.y); A[2]=-expf(av0.z); A[3]=-expf(av0.w);
        A[4]=-expf(av1.x); A[5]=-expf(av1.y); A[6]=-expf(av1.z); A[7]=-expf(av1.w);
        A[8]=-expf(av2.x); A[9]=-expf(av2.y); A[10]=-expf(av2.z); A[11]=-expf(av2.w);
        A[12]=-expf(av3.x); A[13]=-expf(av3.y); A[14]=-expf(av3.z); A[15]=-expf(av3.w);
        #pragma unroll
        for (int n = 0; n < 16; ++n) h[n] = 0.f;
        const float4* wd4 = (const float4*)(Wdt + ((size_t)il * DI + d) * 16);
        float4 w0 = wd4[0], w1 = wd4[1], w2 = wd4[2], w3 = wd4[3];
        float bdtv = bdt[(size_t)il * DI + d];
        float dv   = Dp[(size_t)il * DI + d];
        const float* z_ws = ws + OFF_Z + ((size_t)i * NTOK + b * 5) * DI + d;
        float* y_ws       = ws + OFF_Y + ((size_t)i * NTOK + b * 5) * DI + d;
        #pragma unroll
        for (int t = 0; t < 5; ++t) {
            const float* db = dbl_l + t * 48;
            float acc = bdtv;
            acc += db[0]*w0.x + db[1]*w0.y + db[2]*w0.z + db[3]*w0.w;
            acc += db[4]*w1.x + db[5]*w1.y + db[6]*w1.z + db[7]*w1.w;
            acc += db[8]*w2.x + db[9]*w2.y + db[10]*w2.z + db[11]*w2.w;
            acc += db[12]*w3.x + db[13]*w3.y + db[14]*w3.z + db[15]*w3.w;
            float dtv = fmaxf(acc, 0.f) + log1pf(expf(-fabsf(acc)));
            float xv  = xc_l[t * DI + d];
            float zv  = z_ws[t * DI];
            float dx  = dtv * xv;
            float yacc = 0.f;
            #pragma unroll
            for (int n = 0; n < 16; ++n) {
                h[n] = expf(dtv * A[n]) * h[n] + dx * db[16 + n];
                yacc += h[n] * db[32 + n];
            }
            y_ws[t * DI] = (yacc + xv * dv) * silu_f(zv);
        }
    }
}

// ---------------- K_out: out_proj + residual -> a ----------------
// grid 256: tg = blk>>5 (10 tok), i = (blk>>3)&3, s = blk&7 (32 cols)
__global__ __launch_bounds__(256) void K_out(int l, float* __restrict__ ws)
{
    int blk = blockIdx.x;
    int tg = blk >> 5, i = (blk >> 3) & 3, s = blk & 7;
    int il = i * 3 + l;
    int tid = threadIdx.x;
    int t0 = tg * 10;

    __shared__ __align__(16) float y_l[10 * DI];
    __shared__ __align__(16) float part[2560];

    const float4* ysrc = (const float4*)(ws + OFF_Y + ((size_t)i * NTOK + t0) * DI);
    for (int v = tid; v < 1280; v += 256) ((float4*)y_l)[v] = ysrc[v];
    __syncthreads();

    // thread = (col j, k-split kq of 8); 10 token accumulators
    {
        int j = tid & 31, kq = tid >> 5;
        const float4* wp = (const float4*)(ws + OFF_WOUTR) + ((size_t)il * 8 + s) * 4096 + j;
        const float4* yy = (const float4*)y_l;   // [10][128]
        float acc[10];
        #pragma unroll
        for (int r = 0; r < 10; ++r) acc[r] = 0.f;
        #pragma unroll 4
        for (int kk = 0; kk < 16; ++kk) {
            int k4 = kq * 16 + kk;
            float4 w = wp[(size_t)k4 * 32];
            #pragma unroll
            for (int r = 0; r < 10; ++r) acc[r] += dot4(w, yy[r * 128 + k4]);
        }
        #pragma unroll
        for (int r = 0; r < 10; ++r) part[kq * 320 + r * 32 + j] = acc[r];
    }
    __syncthreads();
    for (int v = tid; v < 320; v += 256) {
        int r = v >> 5, j = v & 31;
        int n = t0 + r, c = 32 * s + j;
        float sum = ws[OFF_ALN + ((size_t)i * NTOK + n) * DM + c];
        #pragma unroll
        for (int kq = 0; kq < 8; ++kq) sum += part[kq * 320 + v];
        ws[OFF_A + ((size_t)i * NTOK + n) * DM + c] = sum;
    }
}

// ---------------- K_gates: s_g = 1+silu(a@gw^T+gb), permuted ----------------
// grid 256: tg = blk>>5 (10 tok), i = (blk>>3)&3, s = blk&7 (32 cols)
__global__ __launch_bounds__(256) void K_gates(const float* __restrict__ gb,
                                               float* __restrict__ ws)
{
    int blk = blockIdx.x;
    int tg = blk >> 5, i = (blk >> 3) & 3, s = blk & 7;
    int tid = threadIdx.x;
    int t0 = tg * 10;

    __shared__ __align__(16) float a_l[10 * DM];
    __shared__ __align__(16) float part[2560];

    const float4* asrc = (const float4*)(ws + OFF_A + ((size_t)i * NTOK + t0) * DM);
    for (int v = tid; v < 640; v += 256) ((float4*)a_l)[v] = asrc[v];
    __syncthreads();

    {
        int j = tid & 31, kq = tid >> 5;
        const float4* wp = (const float4*)(ws + OFF_GWR) + ((size_t)i * 8 + s) * 2048 + j;
        const float4* aa = (const float4*)a_l;   // [10][64]
        float acc[10];
        #pragma unroll
        for (int r = 0; r < 10; ++r) acc[r] = 0.f;
        #pragma unroll 4
        for (int kk = 0; kk < 8; ++kk) {
            int k4 = kq * 8 + kk;
            float4 w = wp[(size_t)k4 * 32];
            #pragma unroll
            for (int r = 0; r < 10; ++r) acc[r] += dot4(w, aa[r * 64 + k4]);
        }
        #pragma unroll
        for (int r = 0; r < 10; ++r) part[kq * 320 + r * 32 + j] = acc[r];
    }
    __syncthreads();
    for (int v = tid; v < 320; v += 256) {
        int r = v >> 5, j = v & 31;
        int n = t0 + r, c = 32 * s + j;
        float acc = gb[(size_t)i * DM + c];
        #pragma unroll
        for (int kq = 0; kq < 8; ++kq) acc += part[kq * 320 + v];
        int bb = n / 5, tt = n % 5;
        int np = (i == 0) ? n : (tt * 16 + bb);
        ws[OFF_SG + ((size_t)i * NTOK + np) * DM + c] = 1.f + silu_f(acc);
    }
}

// ---------------- fused elementwise: o = x * s[plane], nontemporal ----------
__global__ __launch_bounds__(256) void k_elem(
    const float* __restrict__ x1, const float* __restrict__ x2,
    const float* __restrict__ x3, const float* __restrict__ x4,
    const float* __restrict__ audio, const float* __restrict__ s_g,
    float* __restrict__ out) {
    int b = blockIdx.x;
    int t = threadIdx.x;

    if (b < 512) {
        const float* s = s_g + 3 * NTOK * DM;
        const f32x4* xv = (const f32x4*)x4;
        f32x4* ov = (f32x4*)out;
        const int total4 = 1003520 / 4;
        for (int v = b * 256 + t; v < total4; v += 512 * 256) {
            f32x4 x = __builtin_nontemporal_load(&xv[v]);
#pragma unroll
            for (int j = 0; j < 4; ++j) {
                int idx = v * 4 + j;
                x[j] *= s[idx / 49];
            }
            __builtin_nontemporal_store(x, &ov[v]);
        }
    } else if (b < 1024) {
        const float* s = s_g + 2 * NTOK * DM;
        const f32x4* xv = (const f32x4*)x3;
        f32x4* ov = (f32x4*)(out + 1003520);
        const int total4 = 4014080 / 4;
        for (int v = (b - 512) * 256 + t; v < total4; v += 512 * 256) {
            float f = s[v / 49];
            f32x4 x = __builtin_nontemporal_load(&xv[v]);
            x *= f;
            __builtin_nontemporal_store(x, &ov[v]);
        }
    } else if (b < 2048) {
        const float* s = s_g + 1 * NTOK * DM;
        const f32x4* xv = (const f32x4*)x2;
        f32x4* ov = (f32x4*)(out + 5017600);
        const int total4 = 16056320 / 4;
        for (int v = (b - 1024) * 256 + t; v < total4; v += 1024 * 256) {
            float f = s[v / 196];
            f32x4 x = __builtin_nontemporal_load(&xv[v]);
            x *= f;
            __builtin_nontemporal_store(x, &ov[v]);
        }
    } else if (b < 6144) {
        const float* s = s_g;
        const f32x4* xv = (const f32x4*)x1;
        f32x4* ov = (f32x4*)(out + 21073920);
        const int total4 = 64225280 / 4;
        for (int v = (b - 2048) * 256 + t; v < total4; v += 4096 * 256) {
            float f = s[v / 784];
            f32x4 x = __builtin_nontemporal_load(&xv[v]);
            x *= f;
            __builtin_nontemporal_store(x, &ov[v]);
        }
    } else {
        int idx = (b - 6144) * 256 + t;
        out[85299200 + idx] = audio[idx];
    }
}

extern "C" void kernel_launch(void* const* d_in, const int* in_sizes, int n_in,
                              void* d_out, int out_size, void* d_ws, size_t ws_size,
                              hipStream_t stream) {
    const float* x1        = (const float*)d_in[0];
    const float* x2        = (const float*)d_in[1];
    const float* x3        = (const float*)d_in[2];
    const float* x4        = (const float*)d_in[3];
    const float* audio     = (const float*)d_in[4];
    const float* ln_g      = (const float*)d_in[5];
    const float* ln_b      = (const float*)d_in[6];
    const float* in_proj_w = (const float*)d_in[7];
    const float* conv_w    = (const float*)d_in[8];
    const float* conv_b    = (const float*)d_in[9];
    const float* xproj_w   = (const float*)d_in[10];
    const float* dt_w      = (const float*)d_in[11];
    const float* dt_b      = (const float*)d_in[12];
    const float* A_log     = (const float*)d_in[13];
    const float* Dvec      = (const float*)d_in[14];
    const float* out_proj_w= (const float*)d_in[15];
    const float* gate_w    = (const float*)d_in[16];
    const float* gate_b    = (const float*)d_in[17];

    float* ws = (float*)d_ws;

    k_tr<<<344, 256, 0, stream>>>(in_proj_w, out_proj_w, xproj_w, gate_w, ws);
    for (int l = 0; l < 3; ++l) {
        const float* src = (l == 0) ? audio : (ws + OFF_A);
        int stride = (l == 0) ? 0 : NTOK * DM;
        K_in<<<256, 256, 0, stream>>>(src, stride, ln_g, ln_b, conv_w, conv_b, l, ws);
        K_scan<<<64, 512, 0, stream>>>(dt_w, dt_b, A_log, Dvec, l, ws);
        K_out<<<256, 256, 0, stream>>>(l, ws);
    }
    K_gates<<<256, 256, 0, stream>>>(gate_b, ws);
    k_elem<<<6224, 256, 0, stream>>>(x1, x2, x3, x4, audio, ws + OFF_SG,
                                     (float*)d_out);
}